// Round 9
// baseline (297.473 us; speedup 1.0000x reference)
//
#include <hip/hip_runtime.h>

#define FEAT 128
#define NBIN 1024

typedef __attribute__((ext_vector_type(8))) short short8;
typedef __attribute__((ext_vector_type(4))) float floatx4;
typedef __attribute__((ext_vector_type(4))) unsigned int u32x4;
typedef __attribute__((ext_vector_type(2))) int i32x2;

// bf16 helpers (manual, RNE) — finite data only.
__device__ __forceinline__ unsigned short f2bf(float f) {
    unsigned int u = __float_as_uint(f);
    u += 0x7fffu + ((u >> 16) & 1u);
    return (unsigned short)(u >> 16);
}
__device__ __forceinline__ float bf_lo(unsigned int u) { return __uint_as_float(u << 16); }
__device__ __forceinline__ float bf_hi(unsigned int u) { return __uint_as_float(u & 0xffff0000u); }
__device__ __forceinline__ unsigned int pack2(float a, float b) {
    return (unsigned int)f2bf(a) | ((unsigned int)f2bf(b) << 16);
}

// ===========================================================================
// Fused convert + histogram(+rank) + W-prep (unchanged from r7).
// ===========================================================================
__global__ __launch_bounds__(256) void convert_hist_prep(
        const float* __restrict__ x, unsigned short* __restrict__ xb, long n4,
        const int* __restrict__ dst, int* __restrict__ counts,
        int* __restrict__ rank, int E,
        const float* __restrict__ W1, const float* __restrict__ W2,
        unsigned short* __restrict__ bfW1, unsigned short* __restrict__ bfW2,
        int chB) {
    const int t = threadIdx.x;
    if (blockIdx.x >= chB) {
        const int wsel = blockIdx.x - chB;
        const float* W = wsel ? W2 : W1;
        unsigned short* bfW = wsel ? bfW2 : bfW1;
#pragma unroll
        for (int it = 0; it < 8; it++) {
            const int idx = it * 256 + t;
            const int kc = idx >> 9;
            const int ct = (idx >> 6) & 7;
            const int lane = idx & 63;
            const int quad = lane >> 4;
            const int n = ct * 16 + (lane & 15);
            unsigned short frag[8];
#pragma unroll
            for (int j = 0; j < 8; j++)
                frag[j] = f2bf(W[(kc * 32 + quad * 8 + j) * FEAT + n]);
            *(uint4*)&bfW[(long)idx * 8] = *(uint4*)frag;
        }
        return;
    }
    const long i = (long)blockIdx.x * 256 + t;
    if (i < E) rank[i] = atomicAdd(&counts[dst[i]], 1);
    if (i < n4) {
        const float4 v = *(const float4*)&x[i * 4];
        uint2 p;
        p.x = pack2(v.x, v.y);
        p.y = pack2(v.z, v.w);
        *(uint2*)&xb[i * 4] = p;
    }
}

// ===========================================================================
// Parallel counting sort by degree (unchanged from r7).
// ===========================================================================
__global__ __launch_bounds__(256) void deg_hist(const int* __restrict__ counts,
                                                int* __restrict__ ghist, int N) {
    __shared__ int lh[NBIN];
    const int t = threadIdx.x;
    for (int b = t; b < NBIN; b += 256) lh[b] = 0;
    __syncthreads();
    for (int i = blockIdx.x * 256 + t; i < N; i += gridDim.x * 256)
        atomicAdd(&lh[counts[i]], 1);
    __syncthreads();
    for (int b = t; b < NBIN; b += 256)
        if (lh[b]) atomicAdd(&ghist[b], lh[b]);
}

__global__ __launch_bounds__(64) void bin_scan(const int* __restrict__ ghist,
                                               int* __restrict__ hbase,
                                               int* __restrict__ hebase,
                                               int* __restrict__ gcur,
                                               int* __restrict__ offsets,
                                               int N, int E) {
    const int lane = threadIdx.x;
    int c[16], lb[16], le[16];
    int b0 = 0, e0 = 0;
#pragma unroll
    for (int j = 0; j < 16; j++) {
        const int d = lane * 16 + j;
        c[j] = ghist[d];
        lb[j] = b0; le[j] = e0;
        b0 += c[j]; e0 += c[j] * d;
    }
    int bs = b0, es = e0;
#pragma unroll
    for (int off = 1; off < 64; off <<= 1) {
        int nb = __shfl_up(bs, off), ne = __shfl_up(es, off);
        if (lane >= off) { bs += nb; es += ne; }
    }
    const int bexcl = bs - b0, eexcl = es - e0;
#pragma unroll
    for (int j = 0; j < 16; j++) {
        const int d = lane * 16 + j;
        hbase[d] = lb[j] + bexcl;
        hebase[d] = le[j] + eexcl;
        gcur[d] = lb[j] + bexcl;
    }
    if (lane == 0) offsets[N] = E;
}

__global__ __launch_bounds__(256) void assign_kernel(
        const int* __restrict__ counts, int* __restrict__ gcur,
        const int* __restrict__ hbase, const int* __restrict__ hebase,
        int* __restrict__ perm, int* __restrict__ prank,
        int* __restrict__ offsets, int N, int per) {
    __shared__ int lh[NBIN], lbase[NBIN];
    const int t = threadIdx.x;
    const int lo = blockIdx.x * per;
    const int hi = min(lo + per, N);
    if (lo >= N) return;
    for (int b = t; b < NBIN; b += 256) lh[b] = 0;
    __syncthreads();
    for (int i = lo + t; i < hi; i += 256) atomicAdd(&lh[counts[i]], 1);
    __syncthreads();
    for (int b = t; b < NBIN; b += 256) {
        if (lh[b]) lbase[b] = atomicAdd(&gcur[b], lh[b]);
        lh[b] = 0;
    }
    __syncthreads();
    for (int i = lo + t; i < hi; i += 256) {
        const int d = counts[i];
        const int k = lbase[d] + atomicAdd(&lh[d], 1);
        perm[k] = i;
        prank[i] = k;
        offsets[k] = hebase[d] + (k - hbase[d]) * d;
    }
}

__global__ __launch_bounds__(256) void permute_kernel(const int* __restrict__ src,
                                                      const int* __restrict__ dst,
                                                      const int* __restrict__ rank,
                                                      const int* __restrict__ prank,
                                                      const int* __restrict__ offsets,
                                                      int* __restrict__ sorted_src, int E) {
    const int e = blockIdx.x * 256 + threadIdx.x;
    if (e < E) {
        const int pos = offsets[prank[dst[e]]] + rank[e];
        sorted_src[pos] = src[e];
    }
}

// ===========================================================================
// FUSED gather + MFMA GEMM — counted-vmcnt asm gather (r8), CLAMP BUG FIXED:
// r8 clamped idx-pair positions to end-2, which replaced the LAST edge of
// every odd-degree column with a duplicate of edge d-2 (absmax 6.56). Fix:
// no clamp at all — positions run past the column (max ~13 ints past E for
// the final wave); sorted_src is PADDED by 64 ints in the carve-up, pad
// garbage is range-clamped in ESRC (address safety) and never accumulated
// (JE < d guard). Accumulation order identical to r7.
//
// Pipeline (audited through a batch boundary): depth-2 A/B banks, idx pairs
// in the same vmem FIFO. Steady state: issue 4 row-loads, s_waitcnt
// vmcnt(4) (completes the previous edge's 4), accumulate. vmcnt(5) at step1
// (idx of next batch still in flight), vmcnt(4) at step2 drains it before
// its use at step8. sched_barrier(0) after every waitcnt (compiler hoists
// dependent VALU past asm waitcnt otherwise — guide rule #18).
// ===========================================================================
__device__ __forceinline__ void acc_one(float* a8, const u32x4& u) {
    a8[0] += bf_lo(u[0]); a8[1] += bf_hi(u[0]);
    a8[2] += bf_lo(u[1]); a8[3] += bf_hi(u[1]);
    a8[4] += bf_lo(u[2]); a8[5] += bf_hi(u[2]);
    a8[6] += bf_lo(u[3]); a8[7] += bf_hi(u[3]);
}

#define GLD16(dst, addr, OFF) \
    asm volatile("global_load_dwordx4 %0, %1, off offset:" OFF : "=v"(dst) : "v"(addr))
#define GLD8(dst, addr) \
    asm volatile("global_load_dwordx2 %0, %1, off" : "=v"(dst) : "v"(addr))
#define VMWAIT_(N) asm volatile("s_waitcnt vmcnt(" #N ")" ::: "memory")
#define VMWAIT(N) do { VMWAIT_(N); __builtin_amdgcn_sched_barrier(0); } while (0)

// shfl the src index for edge-in-batch W from the holder lane, clamp to [0,N)
// (clamp handles pad garbage: address stays valid, value never accumulated)
#define ESRC(IDX, W) ({ int _v = __shfl(((W) & 1) ? (IDX)[1] : (IDX)[0], \
                                        (((W) >> 1) << 4) + l15); \
                        _v = (_v < 0 || _v >= N) ? 0 : _v; _v; })

// issue idx pair (2 adjacent edges of this lane's column) for batch B — NO
// position clamp (bug fix); sorted_src is padded.
#define ISSUE_I(IDST, B) do { const long _p = (long)start + ((long)(B) << 3) + tq2; \
    GLD8(IDST, (const char*)ssP + (_p << 2)); } while (0)

// one pipeline step: issue edge WISS of batch (from IDX) into N0..N3,
// wait VMN (static), accumulate C0..C3 (edge JE) if in range.
#define STEP(IDX, WISS, N0, N1, N2, N3, C0, C1, C2, C3, VMN, JE) do { \
    const int _s = ESRC(IDX, WISS); \
    const char* _ea = hP + (((long)_s) << 8) + quadoff; \
    GLD16(N0, _ea, "0"); GLD16(N1, _ea, "64"); \
    GLD16(N2, _ea, "128"); GLD16(N3, _ea, "192"); \
    VMWAIT(VMN); \
    if ((JE) < d) { acc_one(acc[0], C0); acc_one(acc[1], C1); \
                    acc_one(acc[2], C2); acc_one(acc[3], C3); } \
} while (0)

template <bool RELU, bool OUT_BF16>
__global__ __launch_bounds__(128) void gather_gemm(const unsigned short* __restrict__ h,
                                                   const int* __restrict__ offsets,
                                                   const int* __restrict__ sorted_src,
                                                   const int* __restrict__ perm,
                                                   const unsigned short* __restrict__ bfW,
                                                   const float* __restrict__ bias,
                                                   void* __restrict__ out, int N) {
    const int t = threadIdx.x;
    const int wave = t >> 6;
    const int lane = t & 63;
    const int quad = lane >> 4;
    const int l15 = lane & 15;
    const int node = blockIdx.x * 32 + wave * 16 + l15;   // sorted position

    int start = 0, end = 0;
    if (node < N) { start = offsets[node]; end = offsets[node + 1]; }
    const int d = end - start;                 // uniform across quads of a column

    // wave-wide max degree (degree-sorted -> nearly uniform; boundary waves mix)
    int dmax = d;
#pragma unroll
    for (int off = 1; off < 64; off <<= 1) dmax = max(dmax, __shfl_xor(dmax, off));
    const int nb = __builtin_amdgcn_readfirstlane((dmax + 7) >> 3);

    const char* hP = (const char*)h;
    const int* ssP = sorted_src;
    const int quadoff = quad << 4;
    const int tq2 = quad * 2;

    float acc[4][8];
#pragma unroll
    for (int kc = 0; kc < 4; kc++)
#pragma unroll
        for (int j = 0; j < 8; j++) acc[kc][j] = 0.f;

    u32x4 A0, A1, A2, A3, B0, B1, B2, B3;
    i32x2 idxC, idxN;

    if (nb > 0) {
        // ---- prologue: idx batch 0, then edge 0 into A ----
        ISSUE_I(idxC, 0);
        VMWAIT(0);
        {
            const int _s0 = ESRC(idxC, 0);
            const char* _ea = hP + (((long)_s0) << 8) + quadoff;
            GLD16(A0, _ea, "0"); GLD16(A1, _ea, "64");
            GLD16(A2, _ea, "128"); GLD16(A3, _ea, "192");
        }
        // ---- steady loop: 8 unrolled steps per batch, depth-2 pipeline ----
        for (int b = 0; b < nb; b++) {
            ISSUE_I(idxN, b + 1);
            const int j0 = b << 3;
            STEP(idxC, 1, B0, B1, B2, B3, A0, A1, A2, A3, 5, j0 + 0);
            STEP(idxC, 2, A0, A1, A2, A3, B0, B1, B2, B3, 4, j0 + 1);
            STEP(idxC, 3, B0, B1, B2, B3, A0, A1, A2, A3, 4, j0 + 2);
            STEP(idxC, 4, A0, A1, A2, A3, B0, B1, B2, B3, 4, j0 + 3);
            STEP(idxC, 5, B0, B1, B2, B3, A0, A1, A2, A3, 4, j0 + 4);
            STEP(idxC, 6, A0, A1, A2, A3, B0, B1, B2, B3, 4, j0 + 5);
            STEP(idxC, 7, B0, B1, B2, B3, A0, A1, A2, A3, 4, j0 + 6);
            STEP(idxN, 0, A0, A1, A2, A3, B0, B1, B2, B3, 4, j0 + 7);
            idxC = idxN;
        }
        VMWAIT(0);   // drain dangling prefetches before normal codegen resumes
    }

    // acc -> A fragments (register-only; layout already matches).
    short8 afrag[4];
#pragma unroll
    for (int kc = 0; kc < 4; kc++) {
        unsigned short fr[8];
#pragma unroll
        for (int j = 0; j < 8; j++) fr[j] = f2bf(acc[kc][j]);
        afrag[kc] = *(short8*)fr;
    }

    // ---- MFMA phase: B-frags straight from global (L1/L2-hot 32 KB) ----
    floatx4 cacc[8];
#pragma unroll
    for (int ct = 0; ct < 8; ct++) cacc[ct] = (floatx4){0.f, 0.f, 0.f, 0.f};
#pragma unroll
    for (int kc = 0; kc < 4; kc++) {
#pragma unroll
        for (int ct = 0; ct < 8; ct++) {
            const short8 b = *(const short8*)&bfW[((kc * 8 + ct) * 64 + lane) * 8];
            cacc[ct] = __builtin_amdgcn_mfma_f32_16x16x32_bf16(afrag[kc], b, cacc[ct], 0, 0, 0);
        }
    }

    // ---- epilogue: C/D layout col=ct*16+l15, row=quad*4+r; row id via perm.
    int orow[4];
#pragma unroll
    for (int r = 0; r < 4; r++) {
        const int prow = blockIdx.x * 32 + wave * 16 + quad * 4 + r;
        orow[r] = (prow < N) ? perm[prow] : -1;
    }
#pragma unroll
    for (int ct = 0; ct < 8; ct++) {
        const int col = ct * 16 + l15;
        const float bv = bias[col];
#pragma unroll
        for (int r = 0; r < 4; r++) {
            if (orow[r] >= 0) {
                float v = cacc[ct][r] + bv;
                if (RELU) v = fmaxf(v, 0.f);
                if (OUT_BF16)
                    ((unsigned short*)out)[(long)orow[r] * FEAT + col] = f2bf(v);
                else
                    ((float*)out)[(long)orow[r] * FEAT + col] = v;
            }
        }
    }
}

// ===========================================================================
// Pipeline (8 dispatches; bf16 payloads, fp32 accumulation) — r7 structure:
//   memset counts+ghist; convert_hist_prep; deg_hist; bin_scan; assign;
//   permute; gather_gemm x2 (counted-vmcnt asm pipelined, clamp-fixed).
// Linearity: segment_sum((hW)[src]) == (segment_sum h[src]) @ W.
// ===========================================================================
extern "C" void kernel_launch(void* const* d_in, const int* in_sizes, int n_in,
                              void* d_out, int out_size, void* d_ws, size_t ws_size,
                              hipStream_t stream) {
    const float* x  = (const float*)d_in[0];
    const int*   ei = (const int*)d_in[1];
    const float* W1 = (const float*)d_in[2];
    const float* b1 = (const float*)d_in[3];
    const float* W2 = (const float*)d_in[4];
    const float* b2 = (const float*)d_in[5];
    float* out = (float*)d_out;

    const int N = in_sizes[0] / FEAT;
    const int E = in_sizes[1] / 2;
    const int* src = ei;
    const int* dst = ei + E;

    // Workspace carve-up (~58 MB). sorted_src has a 64-int PAD (the asm
    // gather reads idx pairs up to ~13 ints past E by design; pad garbage
    // is range-clamped and never accumulated).
    unsigned short* xb   = (unsigned short*)d_ws;            // N*128 bf16
    unsigned short* h1b  = xb + (size_t)N * FEAT;            // N*128 bf16
    unsigned short* bfW1 = h1b + (size_t)N * FEAT;           // 16384
    unsigned short* bfW2 = bfW1 + 16384;                     // 16384
    int* counts    = (int*)(bfW2 + 16384);                   // [N]
    int* ghist     = counts + N;                             // [NBIN]
    int* gcur      = ghist + NBIN;                           // [NBIN]
    int* hbase     = gcur + NBIN;                            // [NBIN]
    int* hebase    = hbase + NBIN;                           // [NBIN]
    int* offsets   = hebase + NBIN;                          // [N+1]
    int* perm      = offsets + N + 1;                        // [N]
    int* prank     = perm + N;                               // [N]
    int* rank      = prank + N;                              // [E]
    int* sorted_src = rank + E;                              // [E + 64 pad]

    const int eb = (E + 255) / 256;
    const long n4 = (long)N * FEAT / 4;
    const int chB = (int)((n4 + 255) / 256);
    const int per = (N + 127) / 128;

    hipMemsetAsync(counts, 0, (size_t)(N + NBIN) * sizeof(int), stream);
    convert_hist_prep<<<chB + 2, 256, 0, stream>>>(x, xb, n4, dst, counts, rank, E,
                                                   W1, W2, bfW1, bfW2, chB);
    deg_hist<<<128, 256, 0, stream>>>(counts, ghist, N);
    bin_scan<<<1, 64, 0, stream>>>(ghist, hbase, hebase, gcur, offsets, N, E);
    assign_kernel<<<128, 256, 0, stream>>>(counts, gcur, hbase, hebase,
                                           perm, prank, offsets, N, per);
    permute_kernel<<<eb, 256, 0, stream>>>(src, dst, rank, prank, offsets,
                                           sorted_src, E);

    const int fused_blocks = (N + 31) / 32;

    gather_gemm<true, true><<<fused_blocks, 128, 0, stream>>>(
        xb, offsets, sorted_src, perm, bfW1, b1, h1b, N);
    gather_gemm<false, false><<<fused_blocks, 128, 0, stream>>>(
        h1b, offsets, sorted_src, perm, bfW2, b2, out, N);
}

// Round 10
// 257.235 us; speedup vs baseline: 1.1564x; 1.1564x over previous
//
#include <hip/hip_runtime.h>

#define FEAT 128

typedef __attribute__((ext_vector_type(8))) short short8;
typedef __attribute__((ext_vector_type(4))) float floatx4;

// bf16 helpers (manual, RNE) — finite data only.
__device__ __forceinline__ unsigned short f2bf(float f) {
    unsigned int u = __float_as_uint(f);
    u += 0x7fffu + ((u >> 16) & 1u);
    return (unsigned short)(u >> 16);
}
__device__ __forceinline__ float bf_lo(unsigned int u) { return __uint_as_float(u << 16); }
__device__ __forceinline__ float bf_hi(unsigned int u) { return __uint_as_float(u & 0xffff0000u); }
__device__ __forceinline__ unsigned int pack2(float a, float b) {
    return (unsigned int)f2bf(a) | ((unsigned int)f2bf(b) << 16);
}

// ===========================================================================
// Fused convert + histogram(+rank) + W-prep + scan-state init:
//  blocks [0, chB): stream x -> bf16; rank[e] = atomicAdd(counts[dst[e]],1)
//   (the atomic's return value IS the edge's within-bucket rank -> permute
//    is atomic-free: pos = offsets[dst] + rank).
//  blocks chB, chB+1: repack W1/W2 into MFMA fragment order; block chB also
//   initializes the lookback-scan aggregates to -1 (runs before scan_fused
//   in stream order).
// ===========================================================================
__global__ __launch_bounds__(256) void convert_hist_prep(
        const float* __restrict__ x, unsigned short* __restrict__ xb, long n4,
        const int* __restrict__ dst, int* __restrict__ counts,
        int* __restrict__ rank, int E,
        const float* __restrict__ W1, const float* __restrict__ W2,
        unsigned short* __restrict__ bfW1, unsigned short* __restrict__ bfW2,
        int* __restrict__ agg, int chB) {
    const int t = threadIdx.x;
    if (blockIdx.x >= chB) {
        const int wsel = blockIdx.x - chB;
        if (!wsel && t < 128) agg[t] = -1;     // lookback-scan state init
        const float* W = wsel ? W2 : W1;
        unsigned short* bfW = wsel ? bfW2 : bfW1;
#pragma unroll
        for (int it = 0; it < 8; it++) {
            const int idx = it * 256 + t;
            const int kc = idx >> 9;
            const int ct = (idx >> 6) & 7;
            const int lane = idx & 63;
            const int quad = lane >> 4;
            const int n = ct * 16 + (lane & 15);
            unsigned short frag[8];
#pragma unroll
            for (int j = 0; j < 8; j++)
                frag[j] = f2bf(W[(kc * 32 + quad * 8 + j) * FEAT + n]);
            *(uint4*)&bfW[(long)idx * 8] = *(uint4*)frag;
        }
        return;
    }
    const long i = (long)blockIdx.x * 256 + t;
    if (i < E) rank[i] = atomicAdd(&counts[dst[i]], 1);
    if (i < n4) {
        const float4 v = *(const float4*)&x[i * 4];
        uint2 p;
        p.x = pack2(v.x, v.y);
        p.y = pack2(v.z, v.w);
        *(uint2*)&xb[i * 4] = p;
    }
}

// ===========================================================================
// Single-kernel exclusive scan via decoupled lookback (aggregates-only):
// 98 blocks x (256 thr x 4 elems). Each block publishes its local total
// with a device-scope atomicExch (agg init -1 by convert kernel), then wave
// 0 spin-reads ALL predecessor aggregates in parallel (no serial chain —
// predecessors compute concurrently; 98 blocks <= 256 CUs so all resident,
// spin-safe). Replaces scan_chunk + add_base (one graph node fewer).
// ===========================================================================
__global__ __launch_bounds__(256) void scan_fused(const int* __restrict__ counts,
                                                  int* __restrict__ offsets,
                                                  int* __restrict__ agg,
                                                  int N, int E) {
    const int t = threadIdx.x;
    const int b = blockIdx.x;
    const int base = b * 1024 + t * 4;
    int c0 = (base + 0 < N) ? counts[base + 0] : 0;
    int c1 = (base + 1 < N) ? counts[base + 1] : 0;
    int c2 = (base + 2 < N) ? counts[base + 2] : 0;
    int c3 = (base + 3 < N) ? counts[base + 3] : 0;
    const int sum = c0 + c1 + c2 + c3;

    const int lane = t & 63, wv = t >> 6;
    int v = sum;
#pragma unroll
    for (int off = 1; off < 64; off <<= 1) {
        int n = __shfl_up(v, off);
        if (lane >= off) v += n;
    }
    __shared__ int ws[4];
    __shared__ int sbase;
    if (lane == 63) ws[wv] = v;
    __syncthreads();
    int wp = 0;
    for (int w = 0; w < wv; w++) wp += ws[w];
    const int excl = wp + v - sum;

    // publish this block's aggregate (thread 255 holds the block total)
    if (t == 255) atomicExch(&agg[b], wp + v);
    // wave 0: parallel lookback over predecessors' aggregates
    if (t < 64) {
        int s = 0;
        for (int j = t; j < b; j += 64) {
            int a;
            do { a = atomicAdd(&agg[j], 0); } while (a < 0);
            s += a;
        }
#pragma unroll
        for (int off = 32; off; off >>= 1) s += __shfl_down(s, off);
        if (t == 0) sbase = s;
    }
    __syncthreads();
    const int bb = sbase;
    if (base + 0 < N) offsets[base + 0] = bb + excl;
    if (base + 1 < N) offsets[base + 1] = bb + excl + c0;
    if (base + 2 < N) offsets[base + 2] = bb + excl + c0 + c1;
    if (base + 3 < N) offsets[base + 3] = bb + excl + c0 + c1 + c2;
    if (b == 0 && t == 0) offsets[N] = E;
}

// ===========================================================================
// Atomic-free permute: pos = offsets[dst[e]] + rank[e].
// ===========================================================================
__global__ __launch_bounds__(256) void permute_kernel(const int* __restrict__ src,
                                                      const int* __restrict__ dst,
                                                      const int* __restrict__ rank,
                                                      const int* __restrict__ offsets,
                                                      int* __restrict__ sorted_src, int E) {
    const int e = blockIdx.x * 256 + threadIdx.x;
    if (e < E) {
        const int pos = offsets[dst[e]] + rank[e];
        sorted_src[pos] = src[e];
    }
}

// ===========================================================================
// FUSED gather + MFMA GEMM — the known-best compiler-scheduled structure
// (r1/r7: 128 thr, __launch_bounds__(128,8), VGPR 32, ~49 us). Evidence
// r1/r2/r4/r7/r9: duration invariant to occupancy (28-49%), lane balance,
// and hand-pipelining -> the gather runs at the memory system's random-
// access service ceiling (~190 MB @ ~3.9 TB/s). Remaining lever applied
// here: NON-TEMPORAL epilogue stores — the 25-50 MB write stream was
// competing with the random table reads for L2/L3 residency.
// ===========================================================================
template <bool RELU, bool OUT_BF16>
__global__ __launch_bounds__(128, 8) void gather_gemm(const unsigned short* __restrict__ h,
                                                      const int* __restrict__ offsets,
                                                      const int* __restrict__ sorted_src,
                                                      const unsigned short* __restrict__ bfW,
                                                      const float* __restrict__ bias,
                                                      void* __restrict__ out, int N) {
    const int t = threadIdx.x;
    const int wave = t >> 6;
    const int lane = t & 63;
    const int quad = lane >> 4;
    const int l15 = lane & 15;
    const int node = blockIdx.x * 32 + wave * 16 + l15;

    int start = 0, end = 0;
    if (node < N) { start = offsets[node]; end = offsets[node + 1]; }

    const uint4* hb = (const uint4*)h;   // 16 uint4 per 128-feat row
    float acc[4][8];
#pragma unroll
    for (int kc = 0; kc < 4; kc++)
#pragma unroll
        for (int j = 0; j < 8; j++) acc[kc][j] = 0.f;

    // ---- gather phase (lane holds edges quad*2, quad*2+1 of column l15) ----
    int e0 = start + quad * 2;
    int s0 = (e0 < end) ? sorted_src[e0] : 0;
    int s1 = (e0 + 1 < end) ? sorted_src[e0 + 1] : 0;

    for (int eb = start; eb < end; eb += 8) {
        // Prefetch next batch's indices (hides index-load latency).
        const int ne = eb + 8 + quad * 2;
        const int ns0 = (ne < end) ? sorted_src[ne] : 0;
        const int ns1 = (ne + 1 < end) ? sorted_src[ne + 1] : 0;

        const int cnt = min(8, end - eb);
#pragma unroll 8
        for (int j = 0; j < cnt; j++) {
            const int sl = (j >> 1) * 16 + l15;        // lane holding edge eb+j of column l15
            const int s = __shfl((j & 1) ? s1 : s0, sl);
            const long rb = (long)s * 16;
            uint4 u[4];
#pragma unroll
            for (int kc = 0; kc < 4; kc++) u[kc] = hb[rb + kc * 4 + quad];
#pragma unroll
            for (int kc = 0; kc < 4; kc++) {
                acc[kc][0] += bf_lo(u[kc].x); acc[kc][1] += bf_hi(u[kc].x);
                acc[kc][2] += bf_lo(u[kc].y); acc[kc][3] += bf_hi(u[kc].y);
                acc[kc][4] += bf_lo(u[kc].z); acc[kc][5] += bf_hi(u[kc].z);
                acc[kc][6] += bf_lo(u[kc].w); acc[kc][7] += bf_hi(u[kc].w);
            }
        }
        s0 = ns0; s1 = ns1;
    }

    // acc -> A fragments (register-only; layout already matches).
    short8 afrag[4];
#pragma unroll
    for (int kc = 0; kc < 4; kc++) {
        unsigned short fr[8];
#pragma unroll
        for (int j = 0; j < 8; j++) fr[j] = f2bf(acc[kc][j]);
        afrag[kc] = *(short8*)fr;
    }

    // ---- MFMA phase: B-frags straight from global (L1/L2-hot 32 KB) ----
    floatx4 cacc[8];
#pragma unroll
    for (int ct = 0; ct < 8; ct++) cacc[ct] = (floatx4){0.f, 0.f, 0.f, 0.f};
#pragma unroll
    for (int kc = 0; kc < 4; kc++) {
#pragma unroll
        for (int ct = 0; ct < 8; ct++) {
            const short8 b = *(const short8*)&bfW[((kc * 8 + ct) * 64 + lane) * 8];
            cacc[ct] = __builtin_amdgcn_mfma_f32_16x16x32_bf16(afrag[kc], b, cacc[ct], 0, 0, 0);
        }
    }

    // ---- epilogue: C/D layout col=ct*16+l15, row=quad*4+r; NT stores ----
#pragma unroll
    for (int ct = 0; ct < 8; ct++) {
        const int col = ct * 16 + l15;
        const float bv = bias[col];
#pragma unroll
        for (int r = 0; r < 4; r++) {
            const int row = blockIdx.x * 32 + wave * 16 + quad * 4 + r;
            if (row < N) {
                float v = cacc[ct][r] + bv;
                if (RELU) v = fmaxf(v, 0.f);
                if (OUT_BF16)
                    __builtin_nontemporal_store(
                        f2bf(v), &((unsigned short*)out)[(long)row * FEAT + col]);
                else
                    __builtin_nontemporal_store(
                        v, &((float*)out)[(long)row * FEAT + col]);
            }
        }
    }
}

// ===========================================================================
// Pipeline (6 graph nodes; bf16 payloads, fp32 accumulation):
//   memset counts
//   convert_hist_prep: x->bf16 | counts/rank | W-prep | scan-state init
//   scan_fused:        decoupled-lookback exclusive scan -> offsets
//   permute:           atomic-free edge placement
//   h1b = gather_gemm(xb, W1, b1, relu) -> bf16  (NT stores)
//   out = gather_gemm(h1b, W2, b2)      -> fp32  (NT stores)
// Linearity: segment_sum((hW)[src]) == (segment_sum h[src]) @ W.
// ===========================================================================
extern "C" void kernel_launch(void* const* d_in, const int* in_sizes, int n_in,
                              void* d_out, int out_size, void* d_ws, size_t ws_size,
                              hipStream_t stream) {
    const float* x  = (const float*)d_in[0];
    const int*   ei = (const int*)d_in[1];
    const float* W1 = (const float*)d_in[2];
    const float* b1 = (const float*)d_in[3];
    const float* W2 = (const float*)d_in[4];
    const float* b2 = (const float*)d_in[5];
    float* out = (float*)d_out;

    const int N = in_sizes[0] / FEAT;
    const int E = in_sizes[1] / 2;
    const int* src = ei;
    const int* dst = ei + E;

    // Workspace carve-up (~58 MB).
    unsigned short* xb   = (unsigned short*)d_ws;            // N*128 bf16
    unsigned short* h1b  = xb + (size_t)N * FEAT;            // N*128 bf16
    unsigned short* bfW1 = h1b + (size_t)N * FEAT;           // 16384
    unsigned short* bfW2 = bfW1 + 16384;                     // 16384
    int* counts    = (int*)(bfW2 + 16384);                   // [N]
    int* offsets   = counts + N;                             // [N+1]
    int* agg       = offsets + N + 1;                        // [128] scan state
    int* rank      = agg + 128;                              // [E]
    int* sorted_src = rank + E;                              // [E]

    const int eb = (E + 255) / 256;
    const int NB = (N + 1023) / 1024;
    const long n4 = (long)N * FEAT / 4;
    const int chB = (int)((n4 + 255) / 256);

    hipMemsetAsync(counts, 0, (size_t)N * sizeof(int), stream);
    convert_hist_prep<<<chB + 2, 256, 0, stream>>>(x, xb, n4, dst, counts, rank, E,
                                                   W1, W2, bfW1, bfW2, agg, chB);
    scan_fused<<<NB, 256, 0, stream>>>(counts, offsets, agg, N, E);
    permute_kernel<<<eb, 256, 0, stream>>>(src, dst, rank, offsets, sorted_src, E);

    const int fused_blocks = (N + 31) / 32;

    gather_gemm<true, true><<<fused_blocks, 128, 0, stream>>>(
        xb, offsets, sorted_src, bfW1, b1, h1b, N);
    gather_gemm<false, false><<<fused_blocks, 128, 0, stream>>>(
        h1b, offsets, sorted_src, bfW2, b2, out, N);
}

// Round 12
// 239.199 us; speedup vs baseline: 1.2436x; 1.0754x over previous
//
#include <hip/hip_runtime.h>

#define FEAT 128

typedef __attribute__((ext_vector_type(8))) short short8;
typedef __attribute__((ext_vector_type(4))) float floatx4;

// bf16 helpers (manual, RNE) — finite data only.
__device__ __forceinline__ unsigned short f2bf(float f) {
    unsigned int u = __float_as_uint(f);
    u += 0x7fffu + ((u >> 16) & 1u);
    return (unsigned short)(u >> 16);
}
__device__ __forceinline__ float bf_lo(unsigned int u) { return __uint_as_float(u << 16); }
__device__ __forceinline__ float bf_hi(unsigned int u) { return __uint_as_float(u & 0xffff0000u); }
__device__ __forceinline__ unsigned int pack2(float a, float b) {
    return (unsigned int)f2bf(a) | ((unsigned int)f2bf(b) << 16);
}

// ===========================================================================
// Fused convert + histogram(+rank) + W-prep + scan-state init:
//  blocks [0, chB): stream x -> bf16; rank[e] = atomicAdd(counts[dst[e]],1)
//   (the atomic's return value IS the edge's within-bucket rank -> permute
//    is atomic-free: pos = offsets[dst] + rank).
//  blocks chB, chB+1: repack W1/W2 into MFMA fragment order; block chB also
//   initializes the lookback-scan aggregates to -1 (runs before scan_fused
//   in stream order).
// ===========================================================================
__global__ __launch_bounds__(256) void convert_hist_prep(
        const float* __restrict__ x, unsigned short* __restrict__ xb, long n4,
        const int* __restrict__ dst, int* __restrict__ counts,
        int* __restrict__ rank, int E,
        const float* __restrict__ W1, const float* __restrict__ W2,
        unsigned short* __restrict__ bfW1, unsigned short* __restrict__ bfW2,
        int* __restrict__ agg, int chB) {
    const int t = threadIdx.x;
    if (blockIdx.x >= chB) {
        const int wsel = blockIdx.x - chB;
        if (!wsel && t < 128) agg[t] = -1;     // lookback-scan state init
        const float* W = wsel ? W2 : W1;
        unsigned short* bfW = wsel ? bfW2 : bfW1;
#pragma unroll
        for (int it = 0; it < 8; it++) {
            const int idx = it * 256 + t;
            const int kc = idx >> 9;
            const int ct = (idx >> 6) & 7;
            const int lane = idx & 63;
            const int quad = lane >> 4;
            const int n = ct * 16 + (lane & 15);
            unsigned short frag[8];
#pragma unroll
            for (int j = 0; j < 8; j++)
                frag[j] = f2bf(W[(kc * 32 + quad * 8 + j) * FEAT + n]);
            *(uint4*)&bfW[(long)idx * 8] = *(uint4*)frag;
        }
        return;
    }
    const long i = (long)blockIdx.x * 256 + t;
    if (i < E) rank[i] = atomicAdd(&counts[dst[i]], 1);
    if (i < n4) {
        const float4 v = *(const float4*)&x[i * 4];
        uint2 p;
        p.x = pack2(v.x, v.y);
        p.y = pack2(v.z, v.w);
        *(uint2*)&xb[i * 4] = p;
    }
}

// ===========================================================================
// Single-kernel exclusive scan via decoupled lookback (aggregates-only):
// 98 blocks x (256 thr x 4 elems). Each block publishes its local total
// with a device-scope atomicExch (agg init -1 by convert kernel), then wave
// 0 spin-reads ALL predecessor aggregates in parallel (98 blocks <= 256 CUs
// so all resident, spin-safe). Replaces scan_chunk + add_base.
// ===========================================================================
__global__ __launch_bounds__(256) void scan_fused(const int* __restrict__ counts,
                                                  int* __restrict__ offsets,
                                                  int* __restrict__ agg,
                                                  int N, int E) {
    const int t = threadIdx.x;
    const int b = blockIdx.x;
    const int base = b * 1024 + t * 4;
    int c0 = (base + 0 < N) ? counts[base + 0] : 0;
    int c1 = (base + 1 < N) ? counts[base + 1] : 0;
    int c2 = (base + 2 < N) ? counts[base + 2] : 0;
    int c3 = (base + 3 < N) ? counts[base + 3] : 0;
    const int sum = c0 + c1 + c2 + c3;

    const int lane = t & 63, wv = t >> 6;
    int v = sum;
#pragma unroll
    for (int off = 1; off < 64; off <<= 1) {
        int n = __shfl_up(v, off);
        if (lane >= off) v += n;
    }
    __shared__ int ws[4];
    __shared__ int sbase;
    if (lane == 63) ws[wv] = v;
    __syncthreads();
    int wp = 0;
    for (int w = 0; w < wv; w++) wp += ws[w];
    const int excl = wp + v - sum;

    // publish this block's aggregate (thread 255 holds the block total)
    if (t == 255) atomicExch(&agg[b], wp + v);
    // wave 0: parallel lookback over predecessors' aggregates
    if (t < 64) {
        int s = 0;
        for (int j = t; j < b; j += 64) {
            int a;
            do { a = atomicAdd(&agg[j], 0); } while (a < 0);
            s += a;
        }
#pragma unroll
        for (int off = 32; off; off >>= 1) s += __shfl_down(s, off);
        if (t == 0) sbase = s;
    }
    __syncthreads();
    const int bb = sbase;
    if (base + 0 < N) offsets[base + 0] = bb + excl;
    if (base + 1 < N) offsets[base + 1] = bb + excl + c0;
    if (base + 2 < N) offsets[base + 2] = bb + excl + c0 + c1;
    if (base + 3 < N) offsets[base + 3] = bb + excl + c0 + c1 + c2;
    if (b == 0 && t == 0) offsets[N] = E;
}

// ===========================================================================
// Atomic-free permute: pos = offsets[dst[e]] + rank[e].
// ===========================================================================
__global__ __launch_bounds__(256) void permute_kernel(const int* __restrict__ src,
                                                      const int* __restrict__ dst,
                                                      const int* __restrict__ rank,
                                                      const int* __restrict__ offsets,
                                                      int* __restrict__ sorted_src, int E) {
    const int e = blockIdx.x * 256 + threadIdx.x;
    if (e < E) {
        const int pos = offsets[dst[e]] + rank[e];
        sorted_src[pos] = src[e];
    }
}

// ===========================================================================
// FUSED gather + MFMA GEMM — the known-best compiler-scheduled structure
// (r1/r7: 128 thr, __launch_bounds__(128,8), VGPR 32, ~49 us). Evidence
// r1/r2/r4/r7/r9: duration invariant to occupancy (28-49%), lane balance,
// and hand-pipelining -> the gather runs at the memory system's random-
// access service ceiling (~190 MB serviced @ ~3.9 TB/s incl. L2 hits).
// r10: NT epilogue stores REGRESS +15 us/dispatch (store path cost >> any
// L2-residency benefit) — plain stores restored.
// ===========================================================================
template <bool RELU, bool OUT_BF16>
__global__ __launch_bounds__(128, 8) void gather_gemm(const unsigned short* __restrict__ h,
                                                      const int* __restrict__ offsets,
                                                      const int* __restrict__ sorted_src,
                                                      const unsigned short* __restrict__ bfW,
                                                      const float* __restrict__ bias,
                                                      void* __restrict__ out, int N) {
    const int t = threadIdx.x;
    const int wave = t >> 6;
    const int lane = t & 63;
    const int quad = lane >> 4;
    const int l15 = lane & 15;
    const int node = blockIdx.x * 32 + wave * 16 + l15;

    int start = 0, end = 0;
    if (node < N) { start = offsets[node]; end = offsets[node + 1]; }

    const uint4* hb = (const uint4*)h;   // 16 uint4 per 128-feat row
    float acc[4][8];
#pragma unroll
    for (int kc = 0; kc < 4; kc++)
#pragma unroll
        for (int j = 0; j < 8; j++) acc[kc][j] = 0.f;

    // ---- gather phase (lane holds edges quad*2, quad*2+1 of column l15) ----
    int e0 = start + quad * 2;
    int s0 = (e0 < end) ? sorted_src[e0] : 0;
    int s1 = (e0 + 1 < end) ? sorted_src[e0 + 1] : 0;

    for (int eb = start; eb < end; eb += 8) {
        // Prefetch next batch's indices (hides index-load latency).
        const int ne = eb + 8 + quad * 2;
        const int ns0 = (ne < end) ? sorted_src[ne] : 0;
        const int ns1 = (ne + 1 < end) ? sorted_src[ne + 1] : 0;

        const int cnt = min(8, end - eb);
#pragma unroll 8
        for (int j = 0; j < cnt; j++) {
            const int sl = (j >> 1) * 16 + l15;        // lane holding edge eb+j of column l15
            const int s = __shfl((j & 1) ? s1 : s0, sl);
            const long rb = (long)s * 16;
            uint4 u[4];
#pragma unroll
            for (int kc = 0; kc < 4; kc++) u[kc] = hb[rb + kc * 4 + quad];
#pragma unroll
            for (int kc = 0; kc < 4; kc++) {
                acc[kc][0] += bf_lo(u[kc].x); acc[kc][1] += bf_hi(u[kc].x);
                acc[kc][2] += bf_lo(u[kc].y); acc[kc][3] += bf_hi(u[kc].y);
                acc[kc][4] += bf_lo(u[kc].z); acc[kc][5] += bf_hi(u[kc].z);
                acc[kc][6] += bf_lo(u[kc].w); acc[kc][7] += bf_hi(u[kc].w);
            }
        }
        s0 = ns0; s1 = ns1;
    }

    // acc -> A fragments (register-only; layout already matches).
    short8 afrag[4];
#pragma unroll
    for (int kc = 0; kc < 4; kc++) {
        unsigned short fr[8];
#pragma unroll
        for (int j = 0; j < 8; j++) fr[j] = f2bf(acc[kc][j]);
        afrag[kc] = *(short8*)fr;
    }

    // ---- MFMA phase: B-frags straight from global (L1/L2-hot 32 KB) ----
    floatx4 cacc[8];
#pragma unroll
    for (int ct = 0; ct < 8; ct++) cacc[ct] = (floatx4){0.f, 0.f, 0.f, 0.f};
#pragma unroll
    for (int kc = 0; kc < 4; kc++) {
#pragma unroll
        for (int ct = 0; ct < 8; ct++) {
            const short8 b = *(const short8*)&bfW[((kc * 8 + ct) * 64 + lane) * 8];
            cacc[ct] = __builtin_amdgcn_mfma_f32_16x16x32_bf16(afrag[kc], b, cacc[ct], 0, 0, 0);
        }
    }

    // ---- epilogue: C/D layout col=ct*16+l15, row=quad*4+r, plain stores ----
#pragma unroll
    for (int ct = 0; ct < 8; ct++) {
        const int col = ct * 16 + l15;
        const float bv = bias[col];
#pragma unroll
        for (int r = 0; r < 4; r++) {
            const int row = blockIdx.x * 32 + wave * 16 + quad * 4 + r;
            if (row < N) {
                float v = cacc[ct][r] + bv;
                if (RELU) v = fmaxf(v, 0.f);
                if (OUT_BF16)
                    ((unsigned short*)out)[(long)row * FEAT + col] = f2bf(v);
                else
                    ((float*)out)[(long)row * FEAT + col] = v;
            }
        }
    }
}

// ===========================================================================
// Pipeline (6 graph nodes; bf16 payloads, fp32 accumulation):
//   memset counts
//   convert_hist_prep: x->bf16 | counts/rank | W-prep | scan-state init
//   scan_fused:        decoupled-lookback exclusive scan -> offsets
//   permute:           atomic-free edge placement
//   h1b = gather_gemm(xb, W1, b1, relu) -> bf16
//   out = gather_gemm(h1b, W2, b2)      -> fp32
// Linearity: segment_sum((hW)[src]) == (segment_sum h[src]) @ W.
// ===========================================================================
extern "C" void kernel_launch(void* const* d_in, const int* in_sizes, int n_in,
                              void* d_out, int out_size, void* d_ws, size_t ws_size,
                              hipStream_t stream) {
    const float* x  = (const float*)d_in[0];
    const int*   ei = (const int*)d_in[1];
    const float* W1 = (const float*)d_in[2];
    const float* b1 = (const float*)d_in[3];
    const float* W2 = (const float*)d_in[4];
    const float* b2 = (const float*)d_in[5];
    float* out = (float*)d_out;

    const int N = in_sizes[0] / FEAT;
    const int E = in_sizes[1] / 2;
    const int* src = ei;
    const int* dst = ei + E;

    // Workspace carve-up (~58 MB).
    unsigned short* xb   = (unsigned short*)d_ws;            // N*128 bf16
    unsigned short* h1b  = xb + (size_t)N * FEAT;            // N*128 bf16
    unsigned short* bfW1 = h1b + (size_t)N * FEAT;           // 16384
    unsigned short* bfW2 = bfW1 + 16384;                     // 16384
    int* counts    = (int*)(bfW2 + 16384);                   // [N]
    int* offsets   = counts + N;                             // [N+1]
    int* agg       = offsets + N + 1;                        // [128] scan state
    int* rank      = agg + 128;                              // [E]
    int* sorted_src = rank + E;                              // [E]

    const int eb = (E + 255) / 256;
    const int NB = (N + 1023) / 1024;
    const long n4 = (long)N * FEAT / 4;
    const int chB = (int)((n4 + 255) / 256);

    hipMemsetAsync(counts, 0, (size_t)N * sizeof(int), stream);
    convert_hist_prep<<<chB + 2, 256, 0, stream>>>(x, xb, n4, dst, counts, rank, E,
                                                   W1, W2, bfW1, bfW2, agg, chB);
    scan_fused<<<NB, 256, 0, stream>>>(counts, offsets, agg, N, E);
    permute_kernel<<<eb, 256, 0, stream>>>(src, dst, rank, offsets, sorted_src, E);

    const int fused_blocks = (N + 31) / 32;

    gather_gemm<true, true><<<fused_blocks, 128, 0, stream>>>(
        xb, offsets, sorted_src, bfW1, b1, h1b, N);
    gather_gemm<false, false><<<fused_blocks, 128, 0, stream>>>(
        h1b, offsets, sorted_src, bfW2, b2, out, N);
}